// Round 3
// baseline (434.596 us; speedup 1.0000x reference)
//
#include <hip/hip_runtime.h>

// INT8 LSTM cell v9: occupancy fix for lstm_gemm.
// v8 post-mortem: counted-vmcnt inline-asm pipeline regressed 2x (compiler
// still inserts its own vmcnt(0) before the ds_reads it tracks against
// global_load_lds; sched_barrier pins + scratch traffic made it worse).
// Reverted to the proven 2-barrier __syncthreads shape — NO inline asm.
// v9's single change: single-buffered BK=64 (24 KB LDS, was 48 KB dbuf) +
// __launch_bounds__(256,4) -> 4 blocks/CU, ALL 1024 blocks co-resident in
// one generation (v6/v7: 3 fit -> 1.33 ragged generations, Occupancy 17.6%,
// long 1-block/CU tail). m114 mechanism: other blocks' MFMA covers each
// block's barrier drain -> needs resident-block diversity.
// Integer math unchanged -> outputs bitwise-identical (absmax 0.0859375).
//   gates = A @ W^T + b,  A=[x|h] (16384x1024), W=[w_ih|w_hh] (2048x1024)

typedef __attribute__((ext_vector_type(4))) int int4v;
typedef __attribute__((ext_vector_type(8))) short short8;
typedef __attribute__((ext_vector_type(4))) float f32x4;
typedef unsigned int u32;
typedef unsigned short u16;
typedef unsigned char u8;

#define BATCH 16384
#define HID 512
#define KTOT 1024
#define BM 256
#define KSTEPS 16                 // KTOT / 64
#define TILEA_BYTES 16384         // 256 rows * 64 int8 (swizzled)
#define TILEW_BYTES 8192          // 128 rows * 64 int8 (swizzled)
#define BUFBYTES 24576            // A tile + W tile (single buffer)
#define NBM 64
#define NBN 16
#define WSA_BYTES ((size_t)NBM * KSTEPS * TILEA_BYTES)   // 16 MB
#define WSW_BYTES ((size_t)NBN * KSTEPS * TILEW_BYTES)   // 2 MB
#define SCALE_OFF (WSA_BYTES + WSW_BYTES)                // per-row A scales (64 KB)
#define PART_OFF (SCALE_OFF + 65536)                     // 512 W-max partials
#define SW_OFF (PART_OFF + 2048)                         // W scale scalar
#define WS_NEEDED (SW_OFF + 64)
#define PACKA_BLOCKS (BATCH / 4)                         // 4096

__device__ __forceinline__ float sigmoidf_(float v) { return 1.0f / (1.0f + __expf(-v)); }
__device__ __forceinline__ float tanhf_(float v) { return 1.0f - 2.0f / (__expf(2.0f * v) + 1.0f); }

__device__ __forceinline__ void gload_lds16(const void* g, void* l) {
    __builtin_amdgcn_global_load_lds(
        (const __attribute__((address_space(1))) u32*)g,
        (__attribute__((address_space(3))) u32*)l, 16, 0, 0);
}

__device__ __forceinline__ u32 pack4(float a, float b, float c, float d, float inv) {
    int q0 = (int)rintf(a * inv), q1 = (int)rintf(b * inv);
    int q2 = (int)rintf(c * inv), q3 = (int)rintf(d * inv);
    return (q0 & 255) | ((q1 & 255) << 8) | ((q2 & 255) << 16) | ((q3 & 255) << 24);
}

// Swizzled chunk position within a (rows x 64) int8 tile: 2 rows share a
// 128B group (8x16B slots); slot = (((row&1)<<2)|c) ^ ((row>>1)&7).
// ds_read_b128 across 16 consecutive rows at fixed c hits each 4-bank group
// exactly 2x -> free (m136). Tile stays linear for global_load_lds.
__device__ __forceinline__ u32 swz_pos(u32 row, u32 c) {
    return ((row >> 1) << 3) | ((((row & 1) << 2) | c) ^ ((row >> 1) & 7));
}

// ---- Stage 1a (fused): pack A into swizzled tiles + W partial-max. ----
// Blocks [0, 4096): pack_a (one wave per A row). Blocks [4096, 4608): wmax.
__global__ __launch_bounds__(256) void pack_a_wmax(
    const float* __restrict__ x, const float* __restrict__ h_prev,
    const float* __restrict__ w_ih, const float* __restrict__ w_hh,
    u8* __restrict__ wsA, float* __restrict__ aScale, float* __restrict__ part)
{
    const u32 t = threadIdx.x;
    if (blockIdx.x >= PACKA_BLOCKS) {
        const u32 b = blockIdx.x - PACKA_BLOCKS;   // 0..511, 4096 floats each
        const float* src = (b < 256) ? (w_ih + (size_t)b * 4096)
                                     : (w_hh + (size_t)(b - 256) * 4096);
        float am = 0.f;
        const float4* p = (const float4*)src + t;
        #pragma unroll
        for (int j = 0; j < 4; ++j) {
            float4 v = p[j * 256];
            am = fmaxf(am, fmaxf(fmaxf(fabsf(v.x), fabsf(v.y)), fmaxf(fabsf(v.z), fabsf(v.w))));
        }
        #pragma unroll
        for (int o = 32; o >= 1; o >>= 1) am = fmaxf(am, __shfl_xor(am, o, 64));
        __shared__ float red[4];
        if ((t & 63) == 0) red[t >> 6] = am;
        __syncthreads();
        if (t == 0) part[b] = fmaxf(fmaxf(red[0], red[1]), fmaxf(red[2], red[3]));
        return;
    }
    __shared__ float4 stg[4][256];   // 16 KB transpose staging (per-wave slice)
    const u32 lane = t & 63;
    const u32 wv = t >> 6;
    const u32 m = blockIdx.x * 4 + wv;
    // Coalesced load: 64 lanes x 16B = 1KB contiguous per instruction.
    const float4* xr = (const float4*)(x + (size_t)m * 512);
    const float4* hr = (const float4*)(h_prev + (size_t)m * 512);
    float4 v[4];
    v[0] = xr[lane];
    v[1] = xr[lane + 64];
    v[2] = hr[lane];
    v[3] = hr[lane + 64];
    float am = 0.f;
    #pragma unroll
    for (int j = 0; j < 4; ++j)
        am = fmaxf(am, fmaxf(fmaxf(fabsf(v[j].x), fabsf(v[j].y)),
                             fmaxf(fabsf(v[j].z), fabsf(v[j].w))));
    #pragma unroll
    for (int o = 32; o >= 1; o >>= 1) am = fmaxf(am, __shfl_xor(am, o, 64));
    const float inv = (am > 0.f) ? 127.0f / am : 0.f;
    if (lane == 0) aScale[m] = am * (1.0f / 127.0f);

    // In-LDS transpose, XOR-swizzled: logical slot idx stored at
    // idx ^ ((idx>>2)&7). Writes: idx = j*64+lane -> 2-way max.
    // Reads: idx = 4*lane+s -> 2-way max. Same-wave slice -> no barrier.
    #pragma unroll
    for (int j = 0; j < 4; ++j)
        stg[wv][j * 64 + (lane ^ ((lane >> 2) & 7))] = v[j];
    u32 wds[4];
    #pragma unroll
    for (int s = 0; s < 4; ++s) {
        float4 w = stg[wv][(4 * lane + s) ^ (lane & 7)];
        wds[s] = pack4(w.x, w.y, w.z, w.w, inv);
    }
    // Lane owns k = lane*16 .. +16: tile ks = lane>>2, chunk c = lane&3.
    const u32 bm = m >> 8, row = m & 255;
    const u32 ks = lane >> 2, clog = lane & 3;
    const u32 pos = swz_pos(row, clog);
    int4v val = {(int)wds[0], (int)wds[1], (int)wds[2], (int)wds[3]};
    *(int4v*)(wsA + ((((size_t)bm * KSTEPS + ks) << 10) + pos) * 16) = val;
}

// ---- Stage 1b: pack W -> exact int8 swizzled tiles (BK=64 layout). ----
__global__ __launch_bounds__(256) void pack_w(
    const float* __restrict__ w_ih, const float* __restrict__ w_hh,
    const float* __restrict__ part, u8* __restrict__ wsW, float* __restrict__ swOut)
{
    const u32 t = threadIdx.x;
    float am = fmaxf(part[t], part[t + 256]);
    #pragma unroll
    for (int o = 32; o >= 1; o >>= 1) am = fmaxf(am, __shfl_xor(am, o, 64));
    __shared__ float red[4];
    if ((t & 63) == 0) red[t >> 6] = am;
    __syncthreads();
    const float wmax = fmaxf(fmaxf(red[0], red[1]), fmaxf(red[2], red[3]));
    const float inv = 127.0f / wmax;   // exact: W = q*s_w, wmax = 127*s_w
    if (blockIdx.x == 0 && t == 0) *swOut = wmax * (1.0f / 127.0f);

    const u32 widx = blockIdx.x * 256 + t;       // [0, 131072)
    const u32 tile = widx >> 9;                  // bn*16 + ks
    const u32 p = widx & 511;
    const u32 wrowHalf = p >> 3;
    const u32 slot = (p & 7) ^ (wrowHalf & 7);
    const u32 wrow = (wrowHalf << 1) | (slot >> 2);
    const u32 clog = slot & 3;
    const u32 ks = tile & 15, bn = tile >> 4;
    const u32 g = wrow >> 5, rr = wrow & 31;
    const u32 wr = g * 512 + bn * 32 + rr;
    const u32 kglob = ks * 64 + clog * 16;
    const float* src = (kglob < 512) ? (w_ih + (size_t)wr * 512 + kglob)
                                     : (w_hh + (size_t)wr * 512 + (kglob - 512));
    u32 wds[4];
    #pragma unroll
    for (int j = 0; j < 4; ++j) {
        float4 v = *((const float4*)src + j);
        wds[j] = pack4(v.x, v.y, v.z, v.w, inv);
    }
    int4v val = {(int)wds[0], (int)wds[1], (int)wds[2], (int)wds[3]};
    *(int4v*)(wsW + (size_t)widx * 16) = val;
}

// ---- Stage 2: i8 GEMM, single-buffer BK64, 4 blocks/CU, XCD swizzle. ----
__global__ __launch_bounds__(256, 4) void lstm_gemm(
    const u8* __restrict__ wsA, const u8* __restrict__ wsW,
    const float* __restrict__ aScale, const float* __restrict__ swPtr,
    const float* __restrict__ c_prev,
    const float* __restrict__ b_ih, const float* __restrict__ b_hh,
    float* __restrict__ h_out, float* __restrict__ c_out)
{
    __shared__ u8 sB[BUFBYTES];   // [A 16KB][W 8KB], 24 KB -> 4+ blocks/CU

    const int t = threadIdx.x;
    const u32 bid = blockIdx.x;
    const u32 xcd = bid & 7;
    const u32 slot = bid >> 3;                    // 0..127
    const int bm = (int)((slot >> 4) * 8 + xcd);  // 8 bm-panels per XCD
    const int bn = (int)(slot & 15);
    const int n0 = bn * 32;
    const int rowBase = bm * BM;

    const int lane = t & 63;
    const int wv = t >> 6;
    const int colin = lane & 15;
    const int quad = lane >> 4;
    const int stageOff = t * 16;

    int4v acc[4][2][4];  // [row-frag][col-frag][gate]
    #pragma unroll
    for (int rf = 0; rf < 4; ++rf)
        #pragma unroll
        for (int cc = 0; cc < 2; ++cc)
            #pragma unroll
            for (int g = 0; g < 4; ++g)
                acc[rf][cc][g] = (int4v){0, 0, 0, 0};

    const char* gA = (const char*)wsA + (size_t)bm * KSTEPS * TILEA_BYTES;
    const char* gW = (const char*)wsW + (size_t)bn * KSTEPS * TILEW_BYTES;

    // Loop-invariant swizzled LDS byte offsets (A region, W region at +16KB).
    u32 aoffs[4], woffs[8];
    #pragma unroll
    for (int rf = 0; rf < 4; ++rf) {
        const u32 row = (u32)(wv * 64 + rf * 16 + colin);
        aoffs[rf] = swz_pos(row, (u32)quad) * 16;
    }
    #pragma unroll
    for (int cc = 0; cc < 2; ++cc)
        #pragma unroll
        for (int g = 0; g < 4; ++g) {
            const u32 wrow = (u32)(g * 32 + cc * 16 + colin);
            woffs[cc * 4 + g] = 16384u + swz_pos(wrow, (u32)quad) * 16;
        }

    #pragma unroll 1
    for (int ks = 0; ks < KSTEPS; ++ks) {
        __syncthreads();   // WAR: everyone done reading previous tile
        #pragma unroll
        for (int j = 0; j < 4; ++j)
            gload_lds16(gA + (size_t)ks * TILEA_BYTES + j * 4096 + stageOff,
                        (char*)sB + j * 4096 + stageOff);
        #pragma unroll
        for (int j = 0; j < 2; ++j)
            gload_lds16(gW + (size_t)ks * TILEW_BYTES + j * 4096 + stageOff,
                        (char*)sB + 16384 + j * 4096 + stageOff);
        __syncthreads();   // RAW: tile visible (vmcnt drain covered by other blocks)

        int4v af[4];
        #pragma unroll
        for (int rf = 0; rf < 4; ++rf)
            af[rf] = *(const int4v*)((const char*)sB + aoffs[rf]);
        int4v bfr[2][4];
        #pragma unroll
        for (int cc = 0; cc < 2; ++cc)
            #pragma unroll
            for (int g = 0; g < 4; ++g)
                bfr[cc][g] = *(const int4v*)((const char*)sB + woffs[cc * 4 + g]);
        #pragma unroll
        for (int rf = 0; rf < 4; ++rf)
            #pragma unroll
            for (int cc = 0; cc < 2; ++cc)
                #pragma unroll
                for (int g = 0; g < 4; ++g)
                    acc[rf][cc][g] = __builtin_amdgcn_mfma_i32_16x16x64_i8(
                        af[rf], bfr[cc][g], acc[rf][cc][g], 0, 0, 0);
    }

    // Epilogue: dequant (per-row scale * W scale), bias, LSTM math — in-lane.
    const float sw = *swPtr;
    float rsc[4][4];
    #pragma unroll
    for (int rf = 0; rf < 4; ++rf)
        #pragma unroll
        for (int reg = 0; reg < 4; ++reg)
            rsc[rf][reg] = aScale[rowBase + wv * 64 + rf * 16 + quad * 4 + reg] * sw;

    float bsum[2][4];
    #pragma unroll
    for (int cc = 0; cc < 2; ++cc) {
        const int colg = n0 + cc * 16 + colin;
        #pragma unroll
        for (int g = 0; g < 4; ++g)
            bsum[cc][g] = b_ih[g * 512 + colg] + b_hh[g * 512 + colg];
    }

    #pragma unroll
    for (int rf = 0; rf < 4; ++rf)
        #pragma unroll
        for (int cc = 0; cc < 2; ++cc) {
            const int colg = n0 + cc * 16 + colin;
            #pragma unroll
            for (int reg = 0; reg < 4; ++reg) {
                const int row = rowBase + wv * 64 + rf * 16 + quad * 4 + reg;
                const size_t off = (size_t)row * 512 + colg;
                const float s = rsc[rf][reg];
                const float ig = (float)acc[rf][cc][0][reg] * s + bsum[cc][0];
                const float fg = (float)acc[rf][cc][1][reg] * s + bsum[cc][1];
                const float gg = (float)acc[rf][cc][2][reg] * s + bsum[cc][2];
                const float og = (float)acc[rf][cc][3][reg] * s + bsum[cc][3];
                const float cp = __builtin_nontemporal_load(c_prev + off);
                const float cn = sigmoidf_(fg) * cp + sigmoidf_(ig) * tanhf_(gg);
                const float hn = sigmoidf_(og) * tanhf_(cn);
                __builtin_nontemporal_store(hn, h_out + off);
                __builtin_nontemporal_store(cn, c_out + off);
            }
        }
}

// ---- Fallback (round-1 kernel, proven): used only if ws_size < WS_NEEDED ----
#define LDSK 72
__device__ __forceinline__ u16 f2bf(float f) {
    u32 u = __builtin_bit_cast(u32, f);
    u += 0x7FFFu + ((u >> 16) & 1u);
    return (u16)(u >> 16);
}
__global__ __launch_bounds__(256, 3) void lstm_fused_v1(
    const float* __restrict__ x, const float* __restrict__ h_prev,
    const float* __restrict__ c_prev, const float* __restrict__ w_ih,
    const float* __restrict__ w_hh, const float* __restrict__ b_ih,
    const float* __restrict__ b_hh, float* __restrict__ h_out,
    float* __restrict__ c_out)
{
    __shared__ u16 sA[128][LDSK];
    __shared__ u16 sW[128][LDSK];
    const int t = threadIdx.x;
    const int bn = blockIdx.x & 15, bm = blockIdx.x >> 4;
    const int n0 = bn * 32, rowBase = bm * 128;
    const int srow = t >> 4, scol = t & 15;
    const int lane = t & 63, wv = t >> 6, colin = lane & 15, quad = lane >> 4;
    f32x4 acc[2][2][4];
    #pragma unroll
    for (int rf = 0; rf < 2; ++rf)
        #pragma unroll
        for (int cc = 0; cc < 2; ++cc)
            #pragma unroll
            for (int g = 0; g < 4; ++g) acc[rf][cc][g] = (f32x4){0.f, 0.f, 0.f, 0.f};
    for (int k0 = 0; k0 < KTOT; k0 += 64) {
        const int kk = (k0 < 512) ? k0 : (k0 - 512);
        const float* aSrc = (k0 < 512) ? x : h_prev;
        const float* wSrc = (k0 < 512) ? w_ih : w_hh;
        __syncthreads();
        #pragma unroll
        for (int p = 0; p < 8; ++p) {
            const int r = srow + p * 16;
            const float4 av = *(const float4*)(aSrc + (size_t)(rowBase + r) * 512 + kk + scol * 4);
            ushort4 ap; ap.x = f2bf(av.x); ap.y = f2bf(av.y); ap.z = f2bf(av.z); ap.w = f2bf(av.w);
            *(ushort4*)&sA[r][scol * 4] = ap;
            const int gate = r >> 5, rr = r & 31;
            const float4 wvv = *(const float4*)(wSrc + (size_t)(gate * 512 + n0 + rr) * 512 + kk + scol * 4);
            ushort4 wp; wp.x = f2bf(wvv.x); wp.y = f2bf(wvv.y); wp.z = f2bf(wvv.z); wp.w = f2bf(wvv.w);
            *(ushort4*)&sW[r][scol * 4] = wp;
        }
        __syncthreads();
        #pragma unroll
        for (int ks = 0; ks < 2; ++ks) {
            short8 af[2];
            #pragma unroll
            for (int rf = 0; rf < 2; ++rf)
                af[rf] = *(const short8*)&sA[wv * 32 + rf * 16 + colin][ks * 32 + quad * 8];
            short8 bfr[2][4];
            #pragma unroll
            for (int cc = 0; cc < 2; ++cc)
                #pragma unroll
                for (int g = 0; g < 4; ++g)
                    bfr[cc][g] = *(const short8*)&sW[g * 32 + cc * 16 + colin][ks * 32 + quad * 8];
            #pragma unroll
            for (int rf = 0; rf < 2; ++rf)
                #pragma unroll
                for (int cc = 0; cc < 2; ++cc)
                    #pragma unroll
                    for (int g = 0; g < 4; ++g)
                        acc[rf][cc][g] = __builtin_amdgcn_mfma_f32_16x16x32_bf16(
                            af[rf], bfr[cc][g], acc[rf][cc][g], 0, 0, 0);
        }
    }
    float bsum[2][4];
    #pragma unroll
    for (int cc = 0; cc < 2; ++cc) {
        const int colg = n0 + cc * 16 + colin;
        #pragma unroll
        for (int g = 0; g < 4; ++g) bsum[cc][g] = b_ih[g * 512 + colg] + b_hh[g * 512 + colg];
    }
    #pragma unroll
    for (int rf = 0; rf < 2; ++rf)
        #pragma unroll
        for (int cc = 0; cc < 2; ++cc) {
            const int colg = n0 + cc * 16 + colin;
            #pragma unroll
            for (int reg = 0; reg < 4; ++reg) {
                const int row = rowBase + wv * 32 + rf * 16 + quad * 4 + reg;
                const size_t off = (size_t)row * 512 + colg;
                const float ig = acc[rf][cc][0][reg] + bsum[cc][0];
                const float fg = acc[rf][cc][1][reg] + bsum[cc][1];
                const float gg = acc[rf][cc][2][reg] + bsum[cc][2];
                const float og = acc[rf][cc][3][reg] + bsum[cc][3];
                const float cp = c_prev[off];
                const float cn = sigmoidf_(fg) * cp + sigmoidf_(ig) * tanhf_(gg);
                const float hn = sigmoidf_(og) * tanhf_(cn);
                h_out[off] = hn;
                c_out[off] = cn;
            }
        }
}

extern "C" void kernel_launch(void* const* d_in, const int* in_sizes, int n_in,
                              void* d_out, int out_size, void* d_ws, size_t ws_size,
                              hipStream_t stream) {
    const float* x      = (const float*)d_in[0];
    const float* h_prev = (const float*)d_in[1];
    const float* c_prev = (const float*)d_in[2];
    const float* w_ih   = (const float*)d_in[3];
    const float* w_hh   = (const float*)d_in[4];
    const float* b_ih   = (const float*)d_in[5];
    const float* b_hh   = (const float*)d_in[6];
    float* h_out = (float*)d_out;
    float* c_out = h_out + (size_t)BATCH * HID;

    if (ws_size >= WS_NEEDED) {
        u8* wsA = (u8*)d_ws;
        u8* wsW = (u8*)d_ws + WSA_BYTES;
        float* aScale = (float*)((char*)d_ws + SCALE_OFF);
        float* part   = (float*)((char*)d_ws + PART_OFF);
        float* swOut  = (float*)((char*)d_ws + SW_OFF);
        pack_a_wmax<<<PACKA_BLOCKS + 512, 256, 0, stream>>>(x, h_prev, w_ih, w_hh,
                                                            wsA, aScale, part);
        pack_w<<<512, 256, 0, stream>>>(w_ih, w_hh, part, wsW, swOut);
        lstm_gemm<<<NBM * NBN, 256, 0, stream>>>(wsA, wsW, aScale, swOut, c_prev,
                                                 b_ih, b_hh, h_out, c_out);
    } else {
        lstm_fused_v1<<<128 * 16, 256, 0, stream>>>(x, h_prev, c_prev, w_ih, w_hh,
                                                    b_ih, b_hh, h_out, c_out);
    }
}

// Round 4
// 219.040 us; speedup vs baseline: 1.9841x; 1.9841x over previous
//
#include <hip/hip_runtime.h>

// INT8 LSTM cell v10: no-LDS, no-barrier GEMM with fragment-ordered packing.
// Triangulation of v6-v9: registers (128-reg acc) pin us to 2 waves/SIMD, so
// barrier drains can't be hidden by occupancy (v9 spill disaster: (256,4)
// capped VGPR=64 -> 920MB scratch writes) and can't be removed at source
// (v8: compiler re-inserts vmcnt(0)). Structural fix: A has ZERO intra-block
// reuse (waves own disjoint rows) -> LDS staging of A is pure overhead; W is
// 2MB, L2-resident. Pack BOTH operands in per-lane fragment order so each
// MFMA fragment is ONE coalesced global_load_dwordx4:
//   wsA tile (bm,ks): chunk[(row>>4)*64 + kc*16 + (row&15)] = A[row][16 k's]
//   wsW tile (bn,ks): chunk[(cc*4+g)*64 + kc*16 + colin]    = W[wrow][16 k's]
// GEMM loop = 12 coalesced loads + 32 MFMAs per K-step, zero sync. Two
// unsynchronized waves/SIMD drift to complementary phases (m114 overlap).
// Integer math unchanged -> outputs bitwise-identical (absmax 0.0859375).
//   gates = A @ W^T + b,  A=[x|h] (16384x1024), W=[w_ih|w_hh] (2048x1024)

typedef __attribute__((ext_vector_type(4))) int int4v;
typedef __attribute__((ext_vector_type(8))) short short8;
typedef __attribute__((ext_vector_type(4))) float f32x4;
typedef unsigned int u32;
typedef unsigned short u16;
typedef unsigned char u8;

#define BATCH 16384
#define HID 512
#define KTOT 1024
#define BM 256
#define KSTEPS 16                 // KTOT / 64
#define TILEA_BYTES 16384         // 1024 chunks * 16 B (fragment-ordered)
#define TILEW_BYTES 8192          // 512 chunks * 16 B (fragment-ordered)
#define NBM 64
#define NBN 16
#define WSA_BYTES ((size_t)NBM * KSTEPS * TILEA_BYTES)   // 16 MB
#define WSW_BYTES ((size_t)NBN * KSTEPS * TILEW_BYTES)   // 2 MB
#define SCALE_OFF (WSA_BYTES + WSW_BYTES)                // per-row A scales (64 KB)
#define PART_OFF (SCALE_OFF + 65536)                     // 512 W-max partials
#define SW_OFF (PART_OFF + 2048)                         // W scale scalar
#define WS_NEEDED (SW_OFF + 64)
#define PACKA_BLOCKS (BATCH / 4)                         // 4096

__device__ __forceinline__ float sigmoidf_(float v) { return 1.0f / (1.0f + __expf(-v)); }
__device__ __forceinline__ float tanhf_(float v) { return 1.0f - 2.0f / (__expf(2.0f * v) + 1.0f); }

__device__ __forceinline__ u32 pack4(float a, float b, float c, float d, float inv) {
    int q0 = (int)rintf(a * inv), q1 = (int)rintf(b * inv);
    int q2 = (int)rintf(c * inv), q3 = (int)rintf(d * inv);
    return (q0 & 255) | ((q1 & 255) << 8) | ((q2 & 255) << 16) | ((q3 & 255) << 24);
}

// ---- Stage 1a (fused): pack A into fragment-ordered tiles + W partial-max. ----
// Blocks [0, 4096): pack_a (one wave per A row). Blocks [4096, 4608): wmax.
__global__ __launch_bounds__(256) void pack_a_wmax(
    const float* __restrict__ x, const float* __restrict__ h_prev,
    const float* __restrict__ w_ih, const float* __restrict__ w_hh,
    u8* __restrict__ wsA, float* __restrict__ aScale, float* __restrict__ part)
{
    const u32 t = threadIdx.x;
    if (blockIdx.x >= PACKA_BLOCKS) {
        const u32 b = blockIdx.x - PACKA_BLOCKS;   // 0..511, 4096 floats each
        const float* src = (b < 256) ? (w_ih + (size_t)b * 4096)
                                     : (w_hh + (size_t)(b - 256) * 4096);
        float am = 0.f;
        const float4* p = (const float4*)src + t;
        #pragma unroll
        for (int j = 0; j < 4; ++j) {
            float4 v = p[j * 256];
            am = fmaxf(am, fmaxf(fmaxf(fabsf(v.x), fabsf(v.y)), fmaxf(fabsf(v.z), fabsf(v.w))));
        }
        #pragma unroll
        for (int o = 32; o >= 1; o >>= 1) am = fmaxf(am, __shfl_xor(am, o, 64));
        __shared__ float red[4];
        if ((t & 63) == 0) red[t >> 6] = am;
        __syncthreads();
        if (t == 0) part[b] = fmaxf(fmaxf(red[0], red[1]), fmaxf(red[2], red[3]));
        return;
    }
    __shared__ float4 stg[4][256];   // 16 KB transpose staging (per-wave slice)
    const u32 lane = t & 63;
    const u32 wv = t >> 6;
    const u32 m = blockIdx.x * 4 + wv;
    // Coalesced load: 64 lanes x 16B = 1KB contiguous per instruction.
    const float4* xr = (const float4*)(x + (size_t)m * 512);
    const float4* hr = (const float4*)(h_prev + (size_t)m * 512);
    float4 v[4];
    v[0] = xr[lane];
    v[1] = xr[lane + 64];
    v[2] = hr[lane];
    v[3] = hr[lane + 64];
    float am = 0.f;
    #pragma unroll
    for (int j = 0; j < 4; ++j)
        am = fmaxf(am, fmaxf(fmaxf(fabsf(v[j].x), fabsf(v[j].y)),
                             fmaxf(fabsf(v[j].z), fabsf(v[j].w))));
    #pragma unroll
    for (int o = 32; o >= 1; o >>= 1) am = fmaxf(am, __shfl_xor(am, o, 64));
    const float inv = (am > 0.f) ? 127.0f / am : 0.f;
    if (lane == 0) aScale[m] = am * (1.0f / 127.0f);

    // In-LDS transpose, XOR-swizzled (2-way max both sides, same-wave slice).
    #pragma unroll
    for (int j = 0; j < 4; ++j)
        stg[wv][j * 64 + (lane ^ ((lane >> 2) & 7))] = v[j];
    u32 wds[4];
    #pragma unroll
    for (int s = 0; s < 4; ++s) {
        float4 w = stg[wv][(4 * lane + s) ^ (lane & 7)];
        wds[s] = pack4(w.x, w.y, w.z, w.w, inv);
    }
    // Lane owns k = lane*16 .. +16: step ks = lane>>2, k-chunk kc = lane&3.
    // Fragment-ordered dst chunk = (row>>4)*64 + kc*16 + (row&15).
    const u32 bm = m >> 8, row = m & 255;
    const u32 ks = lane >> 2, kc = lane & 3;
    const u32 chunk = ((row >> 4) << 6) | (kc << 4) | (row & 15);
    int4v val = {(int)wds[0], (int)wds[1], (int)wds[2], (int)wds[3]};
    *(int4v*)(wsA + (((size_t)bm * KSTEPS + ks) * 1024 + chunk) * 16) = val;
}

// ---- Stage 1b: pack W -> exact int8 fragment-ordered tiles. ----
// Linear write widx = (bn*16+ks)*512 + f*64 + lane,
//   f = cc*4+g, lane = kc*16+colin;
//   source row = g*512 + bn*32 + cc*16 + colin, k = ks*64 + kc*16 (16 wide).
__global__ __launch_bounds__(256) void pack_w(
    const float* __restrict__ w_ih, const float* __restrict__ w_hh,
    const float* __restrict__ part, u8* __restrict__ wsW, float* __restrict__ swOut)
{
    const u32 t = threadIdx.x;
    float am = fmaxf(part[t], part[t + 256]);
    #pragma unroll
    for (int o = 32; o >= 1; o >>= 1) am = fmaxf(am, __shfl_xor(am, o, 64));
    __shared__ float red[4];
    if ((t & 63) == 0) red[t >> 6] = am;
    __syncthreads();
    const float wmax = fmaxf(fmaxf(red[0], red[1]), fmaxf(red[2], red[3]));
    const float inv = 127.0f / wmax;   // exact: W = q*s_w, wmax = 127*s_w
    if (blockIdx.x == 0 && t == 0) *swOut = wmax * (1.0f / 127.0f);

    const u32 widx = blockIdx.x * 256 + t;       // [0, 131072)
    const u32 tile = widx >> 9;                  // bn*16 + ks
    const u32 ks = tile & 15, bn = tile >> 4;
    const u32 f = (widx >> 6) & 7;
    const u32 cc = f >> 2, g = f & 3;
    const u32 lane = widx & 63;
    const u32 kc = lane >> 4, colin = lane & 15;
    const u32 wr = g * 512 + bn * 32 + cc * 16 + colin;
    const u32 kglob = ks * 64 + kc * 16;
    const float* src = (kglob < 512) ? (w_ih + (size_t)wr * 512 + kglob)
                                     : (w_hh + (size_t)wr * 512 + (kglob - 512));
    u32 wds[4];
    #pragma unroll
    for (int j = 0; j < 4; ++j) {
        float4 v = *((const float4*)src + j);
        wds[j] = pack4(v.x, v.y, v.z, v.w, inv);
    }
    int4v val = {(int)wds[0], (int)wds[1], (int)wds[2], (int)wds[3]};
    *(int4v*)(wsW + (size_t)widx * 16) = val;
}

// ---- Stage 2: i8 GEMM, no LDS, no barriers, fragments direct from L2. ----
__global__ __launch_bounds__(256, 2) void lstm_gemm(
    const u8* __restrict__ wsA, const u8* __restrict__ wsW,
    const float* __restrict__ aScale, const float* __restrict__ swPtr,
    const float* __restrict__ c_prev,
    const float* __restrict__ b_ih, const float* __restrict__ b_hh,
    float* __restrict__ h_out, float* __restrict__ c_out)
{
    const int t = threadIdx.x;
    const u32 bid = blockIdx.x;
    const u32 xcd = bid & 7;
    const u32 slot = bid >> 3;                    // 0..127
    const int bm = (int)((slot >> 4) * 8 + xcd);  // 8 bm-panels per XCD
    const int bn = (int)(slot & 15);
    const int n0 = bn * 32;
    const int rowBase = bm * BM;

    const int lane = t & 63;
    const int wv = t >> 6;
    const int colin = lane & 15;
    const int quad = lane >> 4;

    int4v acc[4][2][4];  // [row-frag][col-frag][gate]
    #pragma unroll
    for (int rf = 0; rf < 4; ++rf)
        #pragma unroll
        for (int cc = 0; cc < 2; ++cc)
            #pragma unroll
            for (int g = 0; g < 4; ++g)
                acc[rf][cc][g] = (int4v){0, 0, 0, 0};

    // Per-lane fragment base addresses (fragment-ordered layout):
    //   A frag rf at gA + ks*16384 + rf*1024   (frag index = wv*4+rf)
    //   W frag f  at gW + ks*8192  + f*1024
    const char* gA = (const char*)wsA + (size_t)bm * KSTEPS * TILEA_BYTES
                     + (size_t)(wv * 4) * 1024 + (size_t)lane * 16;
    const char* gW = (const char*)wsW + (size_t)bn * KSTEPS * TILEW_BYTES
                     + (size_t)lane * 16;

    #pragma unroll 1
    for (int ks = 0; ks < KSTEPS; ++ks) {
        int4v af[4];
        #pragma unroll
        for (int rf = 0; rf < 4; ++rf)
            af[rf] = *(const int4v*)(gA + (size_t)ks * TILEA_BYTES + rf * 1024);
        int4v bfr[2][4];
        #pragma unroll
        for (int cc = 0; cc < 2; ++cc)
            #pragma unroll
            for (int g = 0; g < 4; ++g)
                bfr[cc][g] = *(const int4v*)(gW + (size_t)ks * TILEW_BYTES
                                             + (cc * 4 + g) * 1024);
        #pragma unroll
        for (int rf = 0; rf < 4; ++rf)
            #pragma unroll
            for (int cc = 0; cc < 2; ++cc)
                #pragma unroll
                for (int g = 0; g < 4; ++g)
                    acc[rf][cc][g] = __builtin_amdgcn_mfma_i32_16x16x64_i8(
                        af[rf], bfr[cc][g], acc[rf][cc][g], 0, 0, 0);
    }

    // Epilogue: dequant (per-row scale * W scale), bias, LSTM math — in-lane.
    const float sw = *swPtr;
    float rsc[4][4];
    #pragma unroll
    for (int rf = 0; rf < 4; ++rf)
        #pragma unroll
        for (int reg = 0; reg < 4; ++reg)
            rsc[rf][reg] = aScale[rowBase + wv * 64 + rf * 16 + quad * 4 + reg] * sw;

    float bsum[2][4];
    #pragma unroll
    for (int cc = 0; cc < 2; ++cc) {
        const int colg = n0 + cc * 16 + colin;
        #pragma unroll
        for (int g = 0; g < 4; ++g)
            bsum[cc][g] = b_ih[g * 512 + colg] + b_hh[g * 512 + colg];
    }

    #pragma unroll
    for (int rf = 0; rf < 4; ++rf)
        #pragma unroll
        for (int cc = 0; cc < 2; ++cc) {
            const int colg = n0 + cc * 16 + colin;
            #pragma unroll
            for (int reg = 0; reg < 4; ++reg) {
                const int row = rowBase + wv * 64 + rf * 16 + quad * 4 + reg;
                const size_t off = (size_t)row * 512 + colg;
                const float s = rsc[rf][reg];
                const float ig = (float)acc[rf][cc][0][reg] * s + bsum[cc][0];
                const float fg = (float)acc[rf][cc][1][reg] * s + bsum[cc][1];
                const float gg = (float)acc[rf][cc][2][reg] * s + bsum[cc][2];
                const float og = (float)acc[rf][cc][3][reg] * s + bsum[cc][3];
                const float cp = __builtin_nontemporal_load(c_prev + off);
                const float cn = sigmoidf_(fg) * cp + sigmoidf_(ig) * tanhf_(gg);
                const float hn = sigmoidf_(og) * tanhf_(cn);
                __builtin_nontemporal_store(hn, h_out + off);
                __builtin_nontemporal_store(cn, c_out + off);
            }
        }
}

// ---- Fallback (round-1 kernel, proven): used only if ws_size < WS_NEEDED ----
#define LDSK 72
__device__ __forceinline__ u16 f2bf(float f) {
    u32 u = __builtin_bit_cast(u32, f);
    u += 0x7FFFu + ((u >> 16) & 1u);
    return (u16)(u >> 16);
}
__global__ __launch_bounds__(256, 3) void lstm_fused_v1(
    const float* __restrict__ x, const float* __restrict__ h_prev,
    const float* __restrict__ c_prev, const float* __restrict__ w_ih,
    const float* __restrict__ w_hh, const float* __restrict__ b_ih,
    const float* __restrict__ b_hh, float* __restrict__ h_out,
    float* __restrict__ c_out)
{
    __shared__ u16 sA[128][LDSK];
    __shared__ u16 sW[128][LDSK];
    const int t = threadIdx.x;
    const int bn = blockIdx.x & 15, bm = blockIdx.x >> 4;
    const int n0 = bn * 32, rowBase = bm * 128;
    const int srow = t >> 4, scol = t & 15;
    const int lane = t & 63, wv = t >> 6, colin = lane & 15, quad = lane >> 4;
    f32x4 acc[2][2][4];
    #pragma unroll
    for (int rf = 0; rf < 2; ++rf)
        #pragma unroll
        for (int cc = 0; cc < 2; ++cc)
            #pragma unroll
            for (int g = 0; g < 4; ++g) acc[rf][cc][g] = (f32x4){0.f, 0.f, 0.f, 0.f};
    for (int k0 = 0; k0 < KTOT; k0 += 64) {
        const int kk = (k0 < 512) ? k0 : (k0 - 512);
        const float* aSrc = (k0 < 512) ? x : h_prev;
        const float* wSrc = (k0 < 512) ? w_ih : w_hh;
        __syncthreads();
        #pragma unroll
        for (int p = 0; p < 8; ++p) {
            const int r = srow + p * 16;
            const float4 av = *(const float4*)(aSrc + (size_t)(rowBase + r) * 512 + kk + scol * 4);
            ushort4 ap; ap.x = f2bf(av.x); ap.y = f2bf(av.y); ap.z = f2bf(av.z); ap.w = f2bf(av.w);
            *(ushort4*)&sA[r][scol * 4] = ap;
            const int gate = r >> 5, rr = r & 31;
            const float4 wvv = *(const float4*)(wSrc + (size_t)(gate * 512 + n0 + rr) * 512 + kk + scol * 4);
            ushort4 wp; wp.x = f2bf(wvv.x); wp.y = f2bf(wvv.y); wp.z = f2bf(wvv.z); wp.w = f2bf(wvv.w);
            *(ushort4*)&sW[r][scol * 4] = wp;
        }
        __syncthreads();
        #pragma unroll
        for (int ks = 0; ks < 2; ++ks) {
            short8 af[2];
            #pragma unroll
            for (int rf = 0; rf < 2; ++rf)
                af[rf] = *(const short8*)&sA[wv * 32 + rf * 16 + colin][ks * 32 + quad * 8];
            short8 bfr[2][4];
            #pragma unroll
            for (int cc = 0; cc < 2; ++cc)
                #pragma unroll
                for (int g = 0; g < 4; ++g)
                    bfr[cc][g] = *(const short8*)&sW[g * 32 + cc * 16 + colin][ks * 32 + quad * 8];
            #pragma unroll
            for (int rf = 0; rf < 2; ++rf)
                #pragma unroll
                for (int cc = 0; cc < 2; ++cc)
                    #pragma unroll
                    for (int g = 0; g < 4; ++g)
                        acc[rf][cc][g] = __builtin_amdgcn_mfma_f32_16x16x32_bf16(
                            af[rf], bfr[cc][g], acc[rf][cc][g], 0, 0, 0);
        }
    }
    float bsum[2][4];
    #pragma unroll
    for (int cc = 0; cc < 2; ++cc) {
        const int colg = n0 + cc * 16 + colin;
        #pragma unroll
        for (int g = 0; g < 4; ++g) bsum[cc][g] = b_ih[g * 512 + colg] + b_hh[g * 512 + colg];
    }
    #pragma unroll
    for (int rf = 0; rf < 2; ++rf)
        #pragma unroll
        for (int cc = 0; cc < 2; ++cc) {
            const int colg = n0 + cc * 16 + colin;
            #pragma unroll
            for (int reg = 0; reg < 4; ++reg) {
                const int row = rowBase + wv * 32 + rf * 16 + quad * 4 + reg;
                const size_t off = (size_t)row * 512 + colg;
                const float ig = acc[rf][cc][0][reg] + bsum[cc][0];
                const float fg = acc[rf][cc][1][reg] + bsum[cc][1];
                const float gg = acc[rf][cc][2][reg] + bsum[cc][2];
                const float og = acc[rf][cc][3][reg] + bsum[cc][3];
                const float cp = c_prev[off];
                const float cn = sigmoidf_(fg) * cp + sigmoidf_(ig) * tanhf_(gg);
                const float hn = sigmoidf_(og) * tanhf_(cn);
                h_out[off] = hn;
                c_out[off] = cn;
            }
        }
}

extern "C" void kernel_launch(void* const* d_in, const int* in_sizes, int n_in,
                              void* d_out, int out_size, void* d_ws, size_t ws_size,
                              hipStream_t stream) {
    const float* x      = (const float*)d_in[0];
    const float* h_prev = (const float*)d_in[1];
    const float* c_prev = (const float*)d_in[2];
    const float* w_ih   = (const float*)d_in[3];
    const float* w_hh   = (const float*)d_in[4];
    const float* b_ih   = (const float*)d_in[5];
    const float* b_hh   = (const float*)d_in[6];
    float* h_out = (float*)d_out;
    float* c_out = h_out + (size_t)BATCH * HID;

    if (ws_size >= WS_NEEDED) {
        u8* wsA = (u8*)d_ws;
        u8* wsW = (u8*)d_ws + WSA_BYTES;
        float* aScale = (float*)((char*)d_ws + SCALE_OFF);
        float* part   = (float*)((char*)d_ws + PART_OFF);
        float* swOut  = (float*)((char*)d_ws + SW_OFF);
        pack_a_wmax<<<PACKA_BLOCKS + 512, 256, 0, stream>>>(x, h_prev, w_ih, w_hh,
                                                            wsA, aScale, part);
        pack_w<<<512, 256, 0, stream>>>(w_ih, w_hh, part, wsW, swOut);
        lstm_gemm<<<NBM * NBN, 256, 0, stream>>>(wsA, wsW, aScale, swOut, c_prev,
                                                 b_ih, b_hh, h_out, c_out);
    } else {
        lstm_fused_v1<<<128 * 16, 256, 0, stream>>>(x, h_prev, c_prev, w_ih, w_hh,
                                                    b_ih, b_hh, h_out, c_out);
    }
}

// Round 5
// 218.196 us; speedup vs baseline: 1.9918x; 1.0039x over previous
//
#include <hip/hip_runtime.h>

// INT8 LSTM cell v11: v10 (no-LDS, no-barrier, fragment-ordered packing) +
// register double-buffered K-pipeline.
// v10 post-mortem: all three sync structures (LDS+barriers, dbuf, no-LDS)
// land at 17-19% MfmaUtil because iteration ks+1's loads are WAR-blocked
// behind iteration ks's MFMAs (single fragment set) -> one serial L2/L3
// round-trip (~300-900cy) exposed per K-step (5900cy wall vs 640cy MFMA).
// v11: two NAMED fragment sets (af0/bf0, af1/bf1 - compile-time indexed,
// rule #20), load next step's 12 fragments BEFORE computing current step.
// No barriers anywhere -> compiler emits counted vmcnt (never drains), the
// AITER pattern without inline asm. +48 VGPR (~140 arch + 128 acc = 268,
// well under the 512 spill line; v9's disaster was capping at 128).
// Integer math unchanged -> outputs bitwise-identical (absmax 0.0859375).
//   gates = A @ W^T + b,  A=[x|h] (16384x1024), W=[w_ih|w_hh] (2048x1024)

typedef __attribute__((ext_vector_type(4))) int int4v;
typedef __attribute__((ext_vector_type(8))) short short8;
typedef __attribute__((ext_vector_type(4))) float f32x4;
typedef unsigned int u32;
typedef unsigned short u16;
typedef unsigned char u8;

#define BATCH 16384
#define HID 512
#define KTOT 1024
#define BM 256
#define KSTEPS 16                 // KTOT / 64
#define TILEA_BYTES 16384         // 1024 chunks * 16 B (fragment-ordered)
#define TILEW_BYTES 8192          // 512 chunks * 16 B (fragment-ordered)
#define NBM 64
#define NBN 16
#define WSA_BYTES ((size_t)NBM * KSTEPS * TILEA_BYTES)   // 16 MB
#define WSW_BYTES ((size_t)NBN * KSTEPS * TILEW_BYTES)   // 2 MB
#define SCALE_OFF (WSA_BYTES + WSW_BYTES)                // per-row A scales (64 KB)
#define PART_OFF (SCALE_OFF + 65536)                     // 512 W-max partials
#define SW_OFF (PART_OFF + 2048)                         // W scale scalar
#define WS_NEEDED (SW_OFF + 64)
#define PACKA_BLOCKS (BATCH / 4)                         // 4096

__device__ __forceinline__ float sigmoidf_(float v) { return 1.0f / (1.0f + __expf(-v)); }
__device__ __forceinline__ float tanhf_(float v) { return 1.0f - 2.0f / (__expf(2.0f * v) + 1.0f); }

__device__ __forceinline__ u32 pack4(float a, float b, float c, float d, float inv) {
    int q0 = (int)rintf(a * inv), q1 = (int)rintf(b * inv);
    int q2 = (int)rintf(c * inv), q3 = (int)rintf(d * inv);
    return (q0 & 255) | ((q1 & 255) << 8) | ((q2 & 255) << 16) | ((q3 & 255) << 24);
}

// ---- Stage 1a (fused): pack A into fragment-ordered tiles + W partial-max. ----
// Blocks [0, 4096): pack_a (one wave per A row). Blocks [4096, 4608): wmax.
__global__ __launch_bounds__(256) void pack_a_wmax(
    const float* __restrict__ x, const float* __restrict__ h_prev,
    const float* __restrict__ w_ih, const float* __restrict__ w_hh,
    u8* __restrict__ wsA, float* __restrict__ aScale, float* __restrict__ part)
{
    const u32 t = threadIdx.x;
    if (blockIdx.x >= PACKA_BLOCKS) {
        const u32 b = blockIdx.x - PACKA_BLOCKS;   // 0..511, 4096 floats each
        const float* src = (b < 256) ? (w_ih + (size_t)b * 4096)
                                     : (w_hh + (size_t)(b - 256) * 4096);
        float am = 0.f;
        const float4* p = (const float4*)src + t;
        #pragma unroll
        for (int j = 0; j < 4; ++j) {
            float4 v = p[j * 256];
            am = fmaxf(am, fmaxf(fmaxf(fabsf(v.x), fabsf(v.y)), fmaxf(fabsf(v.z), fabsf(v.w))));
        }
        #pragma unroll
        for (int o = 32; o >= 1; o >>= 1) am = fmaxf(am, __shfl_xor(am, o, 64));
        __shared__ float red[4];
        if ((t & 63) == 0) red[t >> 6] = am;
        __syncthreads();
        if (t == 0) part[b] = fmaxf(fmaxf(red[0], red[1]), fmaxf(red[2], red[3]));
        return;
    }
    __shared__ float4 stg[4][256];   // 16 KB transpose staging (per-wave slice)
    const u32 lane = t & 63;
    const u32 wv = t >> 6;
    const u32 m = blockIdx.x * 4 + wv;
    // Coalesced load: 64 lanes x 16B = 1KB contiguous per instruction.
    const float4* xr = (const float4*)(x + (size_t)m * 512);
    const float4* hr = (const float4*)(h_prev + (size_t)m * 512);
    float4 v[4];
    v[0] = xr[lane];
    v[1] = xr[lane + 64];
    v[2] = hr[lane];
    v[3] = hr[lane + 64];
    float am = 0.f;
    #pragma unroll
    for (int j = 0; j < 4; ++j)
        am = fmaxf(am, fmaxf(fmaxf(fabsf(v[j].x), fabsf(v[j].y)),
                             fmaxf(fabsf(v[j].z), fabsf(v[j].w))));
    #pragma unroll
    for (int o = 32; o >= 1; o >>= 1) am = fmaxf(am, __shfl_xor(am, o, 64));
    const float inv = (am > 0.f) ? 127.0f / am : 0.f;
    if (lane == 0) aScale[m] = am * (1.0f / 127.0f);

    // In-LDS transpose, XOR-swizzled (2-way max both sides, same-wave slice).
    #pragma unroll
    for (int j = 0; j < 4; ++j)
        stg[wv][j * 64 + (lane ^ ((lane >> 2) & 7))] = v[j];
    u32 wds[4];
    #pragma unroll
    for (int s = 0; s < 4; ++s) {
        float4 w = stg[wv][(4 * lane + s) ^ (lane & 7)];
        wds[s] = pack4(w.x, w.y, w.z, w.w, inv);
    }
    // Lane owns k = lane*16 .. +16: step ks = lane>>2, k-chunk kc = lane&3.
    // Fragment-ordered dst chunk = (row>>4)*64 + kc*16 + (row&15).
    const u32 bm = m >> 8, row = m & 255;
    const u32 ks = lane >> 2, kc = lane & 3;
    const u32 chunk = ((row >> 4) << 6) | (kc << 4) | (row & 15);
    int4v val = {(int)wds[0], (int)wds[1], (int)wds[2], (int)wds[3]};
    *(int4v*)(wsA + (((size_t)bm * KSTEPS + ks) * 1024 + chunk) * 16) = val;
}

// ---- Stage 1b: pack W -> exact int8 fragment-ordered tiles. ----
// Linear write widx = (bn*16+ks)*512 + f*64 + lane,
//   f = cc*4+g, lane = kc*16+colin;
//   source row = g*512 + bn*32 + cc*16 + colin, k = ks*64 + kc*16 (16 wide).
__global__ __launch_bounds__(256) void pack_w(
    const float* __restrict__ w_ih, const float* __restrict__ w_hh,
    const float* __restrict__ part, u8* __restrict__ wsW, float* __restrict__ swOut)
{
    const u32 t = threadIdx.x;
    float am = fmaxf(part[t], part[t + 256]);
    #pragma unroll
    for (int o = 32; o >= 1; o >>= 1) am = fmaxf(am, __shfl_xor(am, o, 64));
    __shared__ float red[4];
    if ((t & 63) == 0) red[t >> 6] = am;
    __syncthreads();
    const float wmax = fmaxf(fmaxf(red[0], red[1]), fmaxf(red[2], red[3]));
    const float inv = 127.0f / wmax;   // exact: W = q*s_w, wmax = 127*s_w
    if (blockIdx.x == 0 && t == 0) *swOut = wmax * (1.0f / 127.0f);

    const u32 widx = blockIdx.x * 256 + t;       // [0, 131072)
    const u32 tile = widx >> 9;                  // bn*16 + ks
    const u32 ks = tile & 15, bn = tile >> 4;
    const u32 f = (widx >> 6) & 7;
    const u32 cc = f >> 2, g = f & 3;
    const u32 lane = widx & 63;
    const u32 kc = lane >> 4, colin = lane & 15;
    const u32 wr = g * 512 + bn * 32 + cc * 16 + colin;
    const u32 kglob = ks * 64 + kc * 16;
    const float* src = (kglob < 512) ? (w_ih + (size_t)wr * 512 + kglob)
                                     : (w_hh + (size_t)wr * 512 + (kglob - 512));
    u32 wds[4];
    #pragma unroll
    for (int j = 0; j < 4; ++j) {
        float4 v = *((const float4*)src + j);
        wds[j] = pack4(v.x, v.y, v.z, v.w, inv);
    }
    int4v val = {(int)wds[0], (int)wds[1], (int)wds[2], (int)wds[3]};
    *(int4v*)(wsW + (size_t)widx * 16) = val;
}

// ---- Stage 2: i8 GEMM, no LDS/barriers, register-dbuf K-pipeline. ----
__global__ __launch_bounds__(256, 2) void lstm_gemm(
    const u8* __restrict__ wsA, const u8* __restrict__ wsW,
    const float* __restrict__ aScale, const float* __restrict__ swPtr,
    const float* __restrict__ c_prev,
    const float* __restrict__ b_ih, const float* __restrict__ b_hh,
    float* __restrict__ h_out, float* __restrict__ c_out)
{
    const int t = threadIdx.x;
    const u32 bid = blockIdx.x;
    const u32 xcd = bid & 7;
    const u32 slot = bid >> 3;                    // 0..127
    const int bm = (int)((slot >> 4) * 8 + xcd);  // 8 bm-panels per XCD
    const int bn = (int)(slot & 15);
    const int n0 = bn * 32;
    const int rowBase = bm * BM;

    const int lane = t & 63;
    const int wv = t >> 6;
    const int colin = lane & 15;
    const int quad = lane >> 4;

    int4v acc[4][2][4];  // [row-frag][col-frag][gate]
    #pragma unroll
    for (int rf = 0; rf < 4; ++rf)
        #pragma unroll
        for (int cc = 0; cc < 2; ++cc)
            #pragma unroll
            for (int g = 0; g < 4; ++g)
                acc[rf][cc][g] = (int4v){0, 0, 0, 0};

    // Per-lane fragment base addresses (fragment-ordered layout):
    //   A frag rf at gA + ks*16384 + rf*1024   (frag index = wv*4+rf)
    //   W frag f  at gW + ks*8192  + f*1024
    const char* gA = (const char*)wsA + (size_t)bm * KSTEPS * TILEA_BYTES
                     + (size_t)(wv * 4) * 1024 + (size_t)lane * 16;
    const char* gW = (const char*)wsW + (size_t)bn * KSTEPS * TILEW_BYTES
                     + (size_t)lane * 16;

    // Register double-buffer: two NAMED fragment sets (compile-time indexed).
#define LOADF(KS, AF, BF)                                                       \
    {                                                                           \
        _Pragma("unroll")                                                       \
        for (int rf = 0; rf < 4; ++rf)                                          \
            AF[rf] = *(const int4v*)(gA + (size_t)(KS) * TILEA_BYTES + rf * 1024); \
        _Pragma("unroll")                                                       \
        for (int f = 0; f < 8; ++f)                                             \
            BF[f] = *(const int4v*)(gW + (size_t)(KS) * TILEW_BYTES + f * 1024);   \
    }

#define COMPUTEF(AF, BF)                                                        \
    {                                                                           \
        _Pragma("unroll")                                                       \
        for (int rf = 0; rf < 4; ++rf)                                          \
            _Pragma("unroll")                                                   \
            for (int cc = 0; cc < 2; ++cc)                                      \
                _Pragma("unroll")                                               \
                for (int g = 0; g < 4; ++g)                                     \
                    acc[rf][cc][g] = __builtin_amdgcn_mfma_i32_16x16x64_i8(     \
                        AF[rf], BF[cc * 4 + g], acc[rf][cc][g], 0, 0, 0);       \
    }

    int4v af0[4], bf0[8], af1[4], bf1[8];
    LOADF(0, af0, bf0);
    #pragma unroll 1
    for (int ks = 0; ks < KSTEPS; ks += 2) {
        LOADF(ks + 1, af1, bf1);     // next step's loads in flight under...
        COMPUTEF(af0, bf0);          // ...current step's 32 MFMAs (~640cy)
        if (ks + 2 < KSTEPS) LOADF(ks + 2, af0, bf0);
        COMPUTEF(af1, bf1);
    }
#undef LOADF
#undef COMPUTEF

    // Epilogue: dequant (per-row scale * W scale), bias, LSTM math — in-lane.
    const float sw = *swPtr;
    float rsc[4][4];
    #pragma unroll
    for (int rf = 0; rf < 4; ++rf)
        #pragma unroll
        for (int reg = 0; reg < 4; ++reg)
            rsc[rf][reg] = aScale[rowBase + wv * 64 + rf * 16 + quad * 4 + reg] * sw;

    float bsum[2][4];
    #pragma unroll
    for (int cc = 0; cc < 2; ++cc) {
        const int colg = n0 + cc * 16 + colin;
        #pragma unroll
        for (int g = 0; g < 4; ++g)
            bsum[cc][g] = b_ih[g * 512 + colg] + b_hh[g * 512 + colg];
    }

    #pragma unroll
    for (int rf = 0; rf < 4; ++rf)
        #pragma unroll
        for (int cc = 0; cc < 2; ++cc) {
            const int colg = n0 + cc * 16 + colin;
            #pragma unroll
            for (int reg = 0; reg < 4; ++reg) {
                const int row = rowBase + wv * 64 + rf * 16 + quad * 4 + reg;
                const size_t off = (size_t)row * 512 + colg;
                const float s = rsc[rf][reg];
                const float ig = (float)acc[rf][cc][0][reg] * s + bsum[cc][0];
                const float fg = (float)acc[rf][cc][1][reg] * s + bsum[cc][1];
                const float gg = (float)acc[rf][cc][2][reg] * s + bsum[cc][2];
                const float og = (float)acc[rf][cc][3][reg] * s + bsum[cc][3];
                const float cp = __builtin_nontemporal_load(c_prev + off);
                const float cn = sigmoidf_(fg) * cp + sigmoidf_(ig) * tanhf_(gg);
                const float hn = sigmoidf_(og) * tanhf_(cn);
                __builtin_nontemporal_store(hn, h_out + off);
                __builtin_nontemporal_store(cn, c_out + off);
            }
        }
}

// ---- Fallback (round-1 kernel, proven): used only if ws_size < WS_NEEDED ----
#define LDSK 72
__device__ __forceinline__ u16 f2bf(float f) {
    u32 u = __builtin_bit_cast(u32, f);
    u += 0x7FFFu + ((u >> 16) & 1u);
    return (u16)(u >> 16);
}
__global__ __launch_bounds__(256, 3) void lstm_fused_v1(
    const float* __restrict__ x, const float* __restrict__ h_prev,
    const float* __restrict__ c_prev, const float* __restrict__ w_ih,
    const float* __restrict__ w_hh, const float* __restrict__ b_ih,
    const float* __restrict__ b_hh, float* __restrict__ h_out,
    float* __restrict__ c_out)
{
    __shared__ u16 sA[128][LDSK];
    __shared__ u16 sW[128][LDSK];
    const int t = threadIdx.x;
    const int bn = blockIdx.x & 15, bm = blockIdx.x >> 4;
    const int n0 = bn * 32, rowBase = bm * 128;
    const int srow = t >> 4, scol = t & 15;
    const int lane = t & 63, wv = t >> 6, colin = lane & 15, quad = lane >> 4;
    f32x4 acc[2][2][4];
    #pragma unroll
    for (int rf = 0; rf < 2; ++rf)
        #pragma unroll
        for (int cc = 0; cc < 2; ++cc)
            #pragma unroll
            for (int g = 0; g < 4; ++g) acc[rf][cc][g] = (f32x4){0.f, 0.f, 0.f, 0.f};
    for (int k0 = 0; k0 < KTOT; k0 += 64) {
        const int kk = (k0 < 512) ? k0 : (k0 - 512);
        const float* aSrc = (k0 < 512) ? x : h_prev;
        const float* wSrc = (k0 < 512) ? w_ih : w_hh;
        __syncthreads();
        #pragma unroll
        for (int p = 0; p < 8; ++p) {
            const int r = srow + p * 16;
            const float4 av = *(const float4*)(aSrc + (size_t)(rowBase + r) * 512 + kk + scol * 4);
            ushort4 ap; ap.x = f2bf(av.x); ap.y = f2bf(av.y); ap.z = f2bf(av.z); ap.w = f2bf(av.w);
            *(ushort4*)&sA[r][scol * 4] = ap;
            const int gate = r >> 5, rr = r & 31;
            const float4 wvv = *(const float4*)(wSrc + (size_t)(gate * 512 + n0 + rr) * 512 + kk + scol * 4);
            ushort4 wp; wp.x = f2bf(wvv.x); wp.y = f2bf(wvv.y); wp.z = f2bf(wvv.z); wp.w = f2bf(wvv.w);
            *(ushort4*)&sW[r][scol * 4] = wp;
        }
        __syncthreads();
        #pragma unroll
        for (int ks = 0; ks < 2; ++ks) {
            short8 af[2];
            #pragma unroll
            for (int rf = 0; rf < 2; ++rf)
                af[rf] = *(const short8*)&sA[wv * 32 + rf * 16 + colin][ks * 32 + quad * 8];
            short8 bfr[2][4];
            #pragma unroll
            for (int cc = 0; cc < 2; ++cc)
                #pragma unroll
                for (int g = 0; g < 4; ++g)
                    bfr[cc][g] = *(const short8*)&sW[g * 32 + cc * 16 + colin][ks * 32 + quad * 8];
            #pragma unroll
            for (int rf = 0; rf < 2; ++rf)
                #pragma unroll
                for (int cc = 0; cc < 2; ++cc)
                    #pragma unroll
                    for (int g = 0; g < 4; ++g)
                        acc[rf][cc][g] = __builtin_amdgcn_mfma_f32_16x16x32_bf16(
                            af[rf], bfr[cc][g], acc[rf][cc][g], 0, 0, 0);
        }
    }
    float bsum[2][4];
    #pragma unroll
    for (int cc = 0; cc < 2; ++cc) {
        const int colg = n0 + cc * 16 + colin;
        #pragma unroll
        for (int g = 0; g < 4; ++g) bsum[cc][g] = b_ih[g * 512 + colg] + b_hh[g * 512 + colg];
    }
    #pragma unroll
    for (int rf = 0; rf < 2; ++rf)
        #pragma unroll
        for (int cc = 0; cc < 2; ++cc) {
            const int colg = n0 + cc * 16 + colin;
            #pragma unroll
            for (int reg = 0; reg < 4; ++reg) {
                const int row = rowBase + wv * 32 + rf * 16 + quad * 4 + reg;
                const size_t off = (size_t)row * 512 + colg;
                const float ig = acc[rf][cc][0][reg] + bsum[cc][0];
                const float fg = acc[rf][cc][1][reg] + bsum[cc][1];
                const float gg = acc[rf][cc][2][reg] + bsum[cc][2];
                const float og = acc[rf][cc][3][reg] + bsum[cc][3];
                const float cp = c_prev[off];
                const float cn = sigmoidf_(fg) * cp + sigmoidf_(ig) * tanhf_(gg);
                const float hn = sigmoidf_(og) * tanhf_(cn);
                h_out[off] = hn;
                c_out[off] = cn;
            }
        }
}

extern "C" void kernel_launch(void* const* d_in, const int* in_sizes, int n_in,
                              void* d_out, int out_size, void* d_ws, size_t ws_size,
                              hipStream_t stream) {
    const float* x      = (const float*)d_in[0];
    const float* h_prev = (const float*)d_in[1];
    const float* c_prev = (const float*)d_in[2];
    const float* w_ih   = (const float*)d_in[3];
    const float* w_hh   = (const float*)d_in[4];
    const float* b_ih   = (const float*)d_in[5];
    const float* b_hh   = (const float*)d_in[6];
    float* h_out = (float*)d_out;
    float* c_out = h_out + (size_t)BATCH * HID;

    if (ws_size >= WS_NEEDED) {
        u8* wsA = (u8*)d_ws;
        u8* wsW = (u8*)d_ws + WSA_BYTES;
        float* aScale = (float*)((char*)d_ws + SCALE_OFF);
        float* part   = (float*)((char*)d_ws + PART_OFF);
        float* swOut  = (float*)((char*)d_ws + SW_OFF);
        pack_a_wmax<<<PACKA_BLOCKS + 512, 256, 0, stream>>>(x, h_prev, w_ih, w_hh,
                                                            wsA, aScale, part);
        pack_w<<<512, 256, 0, stream>>>(w_ih, w_hh, part, wsW, swOut);
        lstm_gemm<<<NBM * NBN, 256, 0, stream>>>(wsA, wsW, aScale, swOut, c_prev,
                                                 b_ih, b_hh, h_out, c_out);
    } else {
        lstm_fused_v1<<<128 * 16, 256, 0, stream>>>(x, h_prev, c_prev, w_ih, w_hh,
                                                    b_ih, b_hh, h_out, c_out);
    }
}

// Round 6
// 210.406 us; speedup vs baseline: 2.0655x; 1.0370x over previous
//
#include <hip/hip_runtime.h>

// INT8 LSTM cell v12: W-in-LDS-once + A-in-reg GEMM (barrier amortization).
// v6-v11 post-mortem: every per-K-step sync structure pins at 17-19% MfmaUtil.
// v12: W panel (128 KB int8 per bn) staged to LDS in TWO 64 KB halves ->
// only 2 barrier-pairs per BLOCK (vs 16): drain cost amortized away instead
// of fought (v8). K-loop has ZERO barriers / ZERO LDS writes: per step =
// 4 A reg-loads (named dbuf af0/af1, only VMEM in loop) + 8 conflict-free
// ds_read_b128 (W, read-only LDS -> freely pipelined) + 32 MFMA.
// LDS 64 KB -> 2 blocks/CU; regs ~236 <= 256 @ (256,2) (v9 lesson: never
// force 4). Integer math unchanged -> bitwise-identical (absmax 0.0859375).
//   gates = A @ W^T + b,  A=[x|h] (16384x1024), W=[w_ih|w_hh] (2048x1024)

typedef __attribute__((ext_vector_type(4))) int int4v;
typedef __attribute__((ext_vector_type(8))) short short8;
typedef __attribute__((ext_vector_type(4))) float f32x4;
typedef unsigned int u32;
typedef unsigned short u16;
typedef unsigned char u8;

#define BATCH 16384
#define HID 512
#define KTOT 1024
#define BM 256
#define KSTEPS 16                 // KTOT / 64
#define TILEA_BYTES 16384         // 1024 chunks * 16 B (fragment-ordered)
#define TILEW_BYTES 8192          // 512 chunks * 16 B (fragment-ordered)
#define NBM 64
#define NBN 16
#define WSA_BYTES ((size_t)NBM * KSTEPS * TILEA_BYTES)   // 16 MB
#define WSW_BYTES ((size_t)NBN * KSTEPS * TILEW_BYTES)   // 2 MB
#define SCALE_OFF (WSA_BYTES + WSW_BYTES)                // per-row A scales (64 KB)
#define PART_OFF (SCALE_OFF + 65536)                     // 512 W-max partials
#define SW_OFF (PART_OFF + 2048)                         // W scale scalar
#define WS_NEEDED (SW_OFF + 64)
#define PACKA_BLOCKS (BATCH / 4)                         // 4096

__device__ __forceinline__ float sigmoidf_(float v) { return 1.0f / (1.0f + __expf(-v)); }
__device__ __forceinline__ float tanhf_(float v) { return 1.0f - 2.0f / (__expf(2.0f * v) + 1.0f); }

__device__ __forceinline__ void gload_lds16(const void* g, void* l) {
    __builtin_amdgcn_global_load_lds(
        (const __attribute__((address_space(1))) u32*)g,
        (__attribute__((address_space(3))) u32*)l, 16, 0, 0);
}

__device__ __forceinline__ u32 pack4(float a, float b, float c, float d, float inv) {
    int q0 = (int)rintf(a * inv), q1 = (int)rintf(b * inv);
    int q2 = (int)rintf(c * inv), q3 = (int)rintf(d * inv);
    return (q0 & 255) | ((q1 & 255) << 8) | ((q2 & 255) << 16) | ((q3 & 255) << 24);
}

// ---- Stage 1a (fused): pack A into fragment-ordered tiles + W partial-max. ----
// Blocks [0, 4096): pack_a (one wave per A row). Blocks [4096, 4608): wmax.
__global__ __launch_bounds__(256) void pack_a_wmax(
    const float* __restrict__ x, const float* __restrict__ h_prev,
    const float* __restrict__ w_ih, const float* __restrict__ w_hh,
    u8* __restrict__ wsA, float* __restrict__ aScale, float* __restrict__ part)
{
    const u32 t = threadIdx.x;
    if (blockIdx.x >= PACKA_BLOCKS) {
        const u32 b = blockIdx.x - PACKA_BLOCKS;   // 0..511, 4096 floats each
        const float* src = (b < 256) ? (w_ih + (size_t)b * 4096)
                                     : (w_hh + (size_t)(b - 256) * 4096);
        float am = 0.f;
        const float4* p = (const float4*)src + t;
        #pragma unroll
        for (int j = 0; j < 4; ++j) {
            float4 v = p[j * 256];
            am = fmaxf(am, fmaxf(fmaxf(fabsf(v.x), fabsf(v.y)), fmaxf(fabsf(v.z), fabsf(v.w))));
        }
        #pragma unroll
        for (int o = 32; o >= 1; o >>= 1) am = fmaxf(am, __shfl_xor(am, o, 64));
        __shared__ float red[4];
        if ((t & 63) == 0) red[t >> 6] = am;
        __syncthreads();
        if (t == 0) part[b] = fmaxf(fmaxf(red[0], red[1]), fmaxf(red[2], red[3]));
        return;
    }
    __shared__ float4 stg[4][256];   // 16 KB transpose staging (per-wave slice)
    const u32 lane = t & 63;
    const u32 wv = t >> 6;
    const u32 m = blockIdx.x * 4 + wv;
    // Coalesced load: 64 lanes x 16B = 1KB contiguous per instruction.
    const float4* xr = (const float4*)(x + (size_t)m * 512);
    const float4* hr = (const float4*)(h_prev + (size_t)m * 512);
    float4 v[4];
    v[0] = xr[lane];
    v[1] = xr[lane + 64];
    v[2] = hr[lane];
    v[3] = hr[lane + 64];
    float am = 0.f;
    #pragma unroll
    for (int j = 0; j < 4; ++j)
        am = fmaxf(am, fmaxf(fmaxf(fabsf(v[j].x), fabsf(v[j].y)),
                             fmaxf(fabsf(v[j].z), fabsf(v[j].w))));
    #pragma unroll
    for (int o = 32; o >= 1; o >>= 1) am = fmaxf(am, __shfl_xor(am, o, 64));
    const float inv = (am > 0.f) ? 127.0f / am : 0.f;
    if (lane == 0) aScale[m] = am * (1.0f / 127.0f);

    // In-LDS transpose, XOR-swizzled (2-way max both sides, same-wave slice).
    #pragma unroll
    for (int j = 0; j < 4; ++j)
        stg[wv][j * 64 + (lane ^ ((lane >> 2) & 7))] = v[j];
    u32 wds[4];
    #pragma unroll
    for (int s = 0; s < 4; ++s) {
        float4 w = stg[wv][(4 * lane + s) ^ (lane & 7)];
        wds[s] = pack4(w.x, w.y, w.z, w.w, inv);
    }
    // Lane owns k = lane*16 .. +16: step ks = lane>>2, k-chunk kc = lane&3.
    // Fragment-ordered dst chunk = (row>>4)*64 + kc*16 + (row&15).
    const u32 bm = m >> 8, row = m & 255;
    const u32 ks = lane >> 2, kc = lane & 3;
    const u32 chunk = ((row >> 4) << 6) | (kc << 4) | (row & 15);
    int4v val = {(int)wds[0], (int)wds[1], (int)wds[2], (int)wds[3]};
    *(int4v*)(wsA + (((size_t)bm * KSTEPS + ks) * 1024 + chunk) * 16) = val;
}

// ---- Stage 1b: pack W -> exact int8 fragment-ordered tiles. ----
// Linear write widx = (bn*16+ks)*512 + f*64 + lane,
//   f = cc*4+g, lane = kc*16+colin;
//   source row = g*512 + bn*32 + cc*16 + colin, k = ks*64 + kc*16 (16 wide).
__global__ __launch_bounds__(256) void pack_w(
    const float* __restrict__ w_ih, const float* __restrict__ w_hh,
    const float* __restrict__ part, u8* __restrict__ wsW, float* __restrict__ swOut)
{
    const u32 t = threadIdx.x;
    float am = fmaxf(part[t], part[t + 256]);
    #pragma unroll
    for (int o = 32; o >= 1; o >>= 1) am = fmaxf(am, __shfl_xor(am, o, 64));
    __shared__ float red[4];
    if ((t & 63) == 0) red[t >> 6] = am;
    __syncthreads();
    const float wmax = fmaxf(fmaxf(red[0], red[1]), fmaxf(red[2], red[3]));
    const float inv = 127.0f / wmax;   // exact: W = q*s_w, wmax = 127*s_w
    if (blockIdx.x == 0 && t == 0) *swOut = wmax * (1.0f / 127.0f);

    const u32 widx = blockIdx.x * 256 + t;       // [0, 131072)
    const u32 tile = widx >> 9;                  // bn*16 + ks
    const u32 ks = tile & 15, bn = tile >> 4;
    const u32 f = (widx >> 6) & 7;
    const u32 cc = f >> 2, g = f & 3;
    const u32 lane = widx & 63;
    const u32 kc = lane >> 4, colin = lane & 15;
    const u32 wr = g * 512 + bn * 32 + cc * 16 + colin;
    const u32 kglob = ks * 64 + kc * 16;
    const float* src = (kglob < 512) ? (w_ih + (size_t)wr * 512 + kglob)
                                     : (w_hh + (size_t)wr * 512 + (kglob - 512));
    u32 wds[4];
    #pragma unroll
    for (int j = 0; j < 4; ++j) {
        float4 v = *((const float4*)src + j);
        wds[j] = pack4(v.x, v.y, v.z, v.w, inv);
    }
    int4v val = {(int)wds[0], (int)wds[1], (int)wds[2], (int)wds[3]};
    *(int4v*)(wsW + (size_t)widx * 16) = val;
}

// ---- Stage 2: i8 GEMM, W-in-LDS (2 half-panel stages), A-in-reg dbuf. ----
__global__ __launch_bounds__(256, 2) void lstm_gemm(
    const u8* __restrict__ wsA, const u8* __restrict__ wsW,
    const float* __restrict__ aScale, const float* __restrict__ swPtr,
    const float* __restrict__ c_prev,
    const float* __restrict__ b_ih, const float* __restrict__ b_hh,
    float* __restrict__ h_out, float* __restrict__ c_out)
{
    __shared__ u8 sW[65536];   // one half (8 K-steps) of the bn W panel

    const int t = threadIdx.x;
    const u32 bid = blockIdx.x;
    const u32 xcd = bid & 7;
    const u32 slot = bid >> 3;                    // 0..127
    const int bm = (int)((slot >> 4) * 8 + xcd);  // 8 bm-panels per XCD
    const int bn = (int)(slot & 15);
    const int n0 = bn * 32;
    const int rowBase = bm * BM;

    const int lane = t & 63;
    const int wv = t >> 6;
    const int colin = lane & 15;
    const int quad = lane >> 4;

    int4v acc[4][2][4];  // [row-frag][col-frag][gate]
    #pragma unroll
    for (int rf = 0; rf < 4; ++rf)
        #pragma unroll
        for (int cc = 0; cc < 2; ++cc)
            #pragma unroll
            for (int g = 0; g < 4; ++g)
                acc[rf][cc][g] = (int4v){0, 0, 0, 0};

    // A fragment base (fragment-ordered): frag rf at gA + ks*16384 + rf*1024.
    const char* gA = (const char*)wsA + (size_t)bm * KSTEPS * TILEA_BYTES
                     + (size_t)(wv * 4) * 1024 + (size_t)lane * 16;
    // W panel for this bn: 128 KB contiguous (16 tiles x 8 KB).
    const char* gW = (const char*)wsW + (size_t)bn * KSTEPS * TILEW_BYTES;
    const char* sWp = (const char*)sW + (size_t)lane * 16;

#define LOADA(KS, AF)                                                           \
    {                                                                           \
        _Pragma("unroll")                                                       \
        for (int rf = 0; rf < 4; ++rf)                                          \
            AF[rf] = *(const int4v*)(gA + (size_t)(KS) * TILEA_BYTES + rf * 1024); \
    }

    // W frags from LDS: ks7 = K-step within the staged half (0..7).
#define COMPW(AF, KS7)                                                          \
    {                                                                           \
        int4v wf[8];                                                            \
        _Pragma("unroll")                                                       \
        for (int f = 0; f < 8; ++f)                                             \
            wf[f] = *(const int4v*)(sWp + (KS7) * TILEW_BYTES + f * 1024);      \
        _Pragma("unroll")                                                       \
        for (int rf = 0; rf < 4; ++rf)                                          \
            _Pragma("unroll")                                                   \
            for (int cc = 0; cc < 2; ++cc)                                      \
                _Pragma("unroll")                                               \
                for (int g = 0; g < 4; ++g)                                     \
                    acc[rf][cc][g] = __builtin_amdgcn_mfma_i32_16x16x64_i8(     \
                        AF[rf], wf[cc * 4 + g], acc[rf][cc][g], 0, 0, 0);       \
    }

    // 64 KB half-panel stage: 16 x gload_lds16 per thread, linear copy.
#define STAGEW(HALF)                                                            \
    {                                                                           \
        _Pragma("unroll")                                                       \
        for (int j = 0; j < 16; ++j)                                            \
            gload_lds16(gW + (size_t)(HALF) * 65536 + j * 4096 + t * 16,        \
                        (char*)sW + j * 4096 + t * 16);                         \
    }

    int4v af0[4], af1[4];
    LOADA(0, af0);
    LOADA(1, af1);
    STAGEW(0);
    __syncthreads();                 // single drain; af0/af1 also land here

    // Half 0: K-steps 0..7. No barriers, no LDS writes inside.
    #pragma unroll 1
    for (int ks = 0; ks < 8; ks += 2) {
        COMPW(af0, ks);
        LOADA(ks + 2, af0);          // ks=6 loads step 8 (consumed after reload)
        COMPW(af1, ks + 1);
        LOADA(ks + 3, af1);          // ks=6 loads step 9
    }

    __syncthreads();                 // all waves done reading half 0
    STAGEW(1);
    __syncthreads();                 // half 1 visible (af prefetch drains too - fine)

    // Half 1: K-steps 8..15. Trailing LOADAs run past the A panel into wsW
    // (valid workspace memory, values never consumed) - cheaper than guards.
    #pragma unroll 1
    for (int ks = 8; ks < 16; ks += 2) {
        COMPW(af0, ks & 7);
        LOADA(ks + 2, af0);
        COMPW(af1, (ks + 1) & 7);
        LOADA(ks + 3, af1);
    }
#undef LOADA
#undef COMPW
#undef STAGEW

    // Epilogue: dequant (per-row scale * W scale), bias, LSTM math — in-lane.
    const float sw = *swPtr;
    float rsc[4][4];
    #pragma unroll
    for (int rf = 0; rf < 4; ++rf)
        #pragma unroll
        for (int reg = 0; reg < 4; ++reg)
            rsc[rf][reg] = aScale[rowBase + wv * 64 + rf * 16 + quad * 4 + reg] * sw;

    float bsum[2][4];
    #pragma unroll
    for (int cc = 0; cc < 2; ++cc) {
        const int colg = n0 + cc * 16 + colin;
        #pragma unroll
        for (int g = 0; g < 4; ++g)
            bsum[cc][g] = b_ih[g * 512 + colg] + b_hh[g * 512 + colg];
    }

    #pragma unroll
    for (int rf = 0; rf < 4; ++rf)
        #pragma unroll
        for (int cc = 0; cc < 2; ++cc) {
            const int colg = n0 + cc * 16 + colin;
            #pragma unroll
            for (int reg = 0; reg < 4; ++reg) {
                const int row = rowBase + wv * 64 + rf * 16 + quad * 4 + reg;
                const size_t off = (size_t)row * 512 + colg;
                const float s = rsc[rf][reg];
                const float ig = (float)acc[rf][cc][0][reg] * s + bsum[cc][0];
                const float fg = (float)acc[rf][cc][1][reg] * s + bsum[cc][1];
                const float gg = (float)acc[rf][cc][2][reg] * s + bsum[cc][2];
                const float og = (float)acc[rf][cc][3][reg] * s + bsum[cc][3];
                const float cp = __builtin_nontemporal_load(c_prev + off);
                const float cn = sigmoidf_(fg) * cp + sigmoidf_(ig) * tanhf_(gg);
                const float hn = sigmoidf_(og) * tanhf_(cn);
                __builtin_nontemporal_store(hn, h_out + off);
                __builtin_nontemporal_store(cn, c_out + off);
            }
        }
}

// ---- Fallback (round-1 kernel, proven): used only if ws_size < WS_NEEDED ----
#define LDSK 72
__device__ __forceinline__ u16 f2bf(float f) {
    u32 u = __builtin_bit_cast(u32, f);
    u += 0x7FFFu + ((u >> 16) & 1u);
    return (u16)(u >> 16);
}
__global__ __launch_bounds__(256, 3) void lstm_fused_v1(
    const float* __restrict__ x, const float* __restrict__ h_prev,
    const float* __restrict__ c_prev, const float* __restrict__ w_ih,
    const float* __restrict__ w_hh, const float* __restrict__ b_ih,
    const float* __restrict__ b_hh, float* __restrict__ h_out,
    float* __restrict__ c_out)
{
    __shared__ u16 sA[128][LDSK];
    __shared__ u16 sW[128][LDSK];
    const int t = threadIdx.x;
    const int bn = blockIdx.x & 15, bm = blockIdx.x >> 4;
    const int n0 = bn * 32, rowBase = bm * 128;
    const int srow = t >> 4, scol = t & 15;
    const int lane = t & 63, wv = t >> 6, colin = lane & 15, quad = lane >> 4;
    f32x4 acc[2][2][4];
    #pragma unroll
    for (int rf = 0; rf < 2; ++rf)
        #pragma unroll
        for (int cc = 0; cc < 2; ++cc)
            #pragma unroll
            for (int g = 0; g < 4; ++g) acc[rf][cc][g] = (f32x4){0.f, 0.f, 0.f, 0.f};
    for (int k0 = 0; k0 < KTOT; k0 += 64) {
        const int kk = (k0 < 512) ? k0 : (k0 - 512);
        const float* aSrc = (k0 < 512) ? x : h_prev;
        const float* wSrc = (k0 < 512) ? w_ih : w_hh;
        __syncthreads();
        #pragma unroll
        for (int p = 0; p < 8; ++p) {
            const int r = srow + p * 16;
            const float4 av = *(const float4*)(aSrc + (size_t)(rowBase + r) * 512 + kk + scol * 4);
            ushort4 ap; ap.x = f2bf(av.x); ap.y = f2bf(av.y); ap.z = f2bf(av.z); ap.w = f2bf(av.w);
            *(ushort4*)&sA[r][scol * 4] = ap;
            const int gate = r >> 5, rr = r & 31;
            const float4 wvv = *(const float4*)(wSrc + (size_t)(gate * 512 + n0 + rr) * 512 + kk + scol * 4);
            ushort4 wp; wp.x = f2bf(wvv.x); wp.y = f2bf(wvv.y); wp.z = f2bf(wvv.z); wp.w = f2bf(wvv.w);
            *(ushort4*)&sW[r][scol * 4] = wp;
        }
        __syncthreads();
        #pragma unroll
        for (int ks = 0; ks < 2; ++ks) {
            short8 af[2];
            #pragma unroll
            for (int rf = 0; rf < 2; ++rf)
                af[rf] = *(const short8*)&sA[wv * 32 + rf * 16 + colin][ks * 32 + quad * 8];
            short8 bfr[2][4];
            #pragma unroll
            for (int cc = 0; cc < 2; ++cc)
                #pragma unroll
                for (int g = 0; g < 4; ++g)
                    bfr[cc][g] = *(const short8*)&sW[g * 32 + cc * 16 + colin][ks * 32 + quad * 8];
            #pragma unroll
            for (int rf = 0; rf < 2; ++rf)
                #pragma unroll
                for (int cc = 0; cc < 2; ++cc)
                    #pragma unroll
                    for (int g = 0; g < 4; ++g)
                        acc[rf][cc][g] = __builtin_amdgcn_mfma_f32_16x16x32_bf16(
                            af[rf], bfr[cc][g], acc[rf][cc][g], 0, 0, 0);
        }
    }
    float bsum[2][4];
    #pragma unroll
    for (int cc = 0; cc < 2; ++cc) {
        const int colg = n0 + cc * 16 + colin;
        #pragma unroll
        for (int g = 0; g < 4; ++g) bsum[cc][g] = b_ih[g * 512 + colg] + b_hh[g * 512 + colg];
    }
    #pragma unroll
    for (int rf = 0; rf < 2; ++rf)
        #pragma unroll
        for (int cc = 0; cc < 2; ++cc) {
            const int colg = n0 + cc * 16 + colin;
            #pragma unroll
            for (int reg = 0; reg < 4; ++reg) {
                const int row = rowBase + wv * 32 + rf * 16 + quad * 4 + reg;
                const size_t off = (size_t)row * 512 + colg;
                const float ig = acc[rf][cc][0][reg] + bsum[cc][0];
                const float fg = acc[rf][cc][1][reg] + bsum[cc][1];
                const float gg = acc[rf][cc][2][reg] + bsum[cc][2];
                const float og = acc[rf][cc][3][reg] + bsum[cc][3];
                const float cp = c_prev[off];
                const float cn = sigmoidf_(fg) * cp + sigmoidf_(ig) * tanhf_(gg);
                const float hn = sigmoidf_(og) * tanhf_(cn);
                h_out[off] = hn;
                c_out[off] = cn;
            }
        }
}

extern "C" void kernel_launch(void* const* d_in, const int* in_sizes, int n_in,
                              void* d_out, int out_size, void* d_ws, size_t ws_size,
                              hipStream_t stream) {
    const float* x      = (const float*)d_in[0];
    const float* h_prev = (const float*)d_in[1];
    const float* c_prev = (const float*)d_in[2];
    const float* w_ih   = (const float*)d_in[3];
    const float* w_hh   = (const float*)d_in[4];
    const float* b_ih   = (const float*)d_in[5];
    const float* b_hh   = (const float*)d_in[6];
    float* h_out = (float*)d_out;
    float* c_out = h_out + (size_t)BATCH * HID;

    if (ws_size >= WS_NEEDED) {
        u8* wsA = (u8*)d_ws;
        u8* wsW = (u8*)d_ws + WSA_BYTES;
        float* aScale = (float*)((char*)d_ws + SCALE_OFF);
        float* part   = (float*)((char*)d_ws + PART_OFF);
        float* swOut  = (float*)((char*)d_ws + SW_OFF);
        pack_a_wmax<<<PACKA_BLOCKS + 512, 256, 0, stream>>>(x, h_prev, w_ih, w_hh,
                                                            wsA, aScale, part);
        pack_w<<<512, 256, 0, stream>>>(w_ih, w_hh, part, wsW, swOut);
        lstm_gemm<<<NBM * NBN, 256, 0, stream>>>(wsA, wsW, aScale, swOut, c_prev,
                                                 b_ih, b_hh, h_out, c_out);
    } else {
        lstm_fused_v1<<<128 * 16, 256, 0, stream>>>(x, h_prev, c_prev, w_ih, w_hh,
                                                    b_ih, b_hh, h_out, c_out);
    }
}